// Round 6
// baseline (718.717 us; speedup 1.0000x reference)
//
#include <hip/hip_runtime.h>
#include <hip/hip_bf16.h>

#define BB 64
#define TT 512
#define HH 256
#define EE 128
#define VV 32000
#define SS 128
#define LL 16

typedef __attribute__((ext_vector_type(8))) short bf16x8;
typedef __attribute__((ext_vector_type(4))) float f32x4;

static __device__ __forceinline__ unsigned short f2bf(float x) {
    unsigned int u = __float_as_uint(x);
    unsigned int r = (u + 0x7fffu + ((u >> 16) & 1u)) >> 16;
    return (unsigned short)r;
}

// tanh(x) = 1 - 2/(exp2(x*2*log2e)+1)
static __device__ __forceinline__ float ftanh(float x) {
    float y = __builtin_amdgcn_exp2f(x * 2.885390082f);
    return 1.f - 2.f * __builtin_amdgcn_rcpf(y + 1.f);
}

// ================= K1 body: {hW, prep_b, embed} by blockIdx =================
__device__ __forceinline__ void pre_body(int blk, int tid,
                                         const float* __restrict__ last_hidden,
                                         const float* __restrict__ attn_W,
                                         const float* __restrict__ attn_b,
                                         const int* __restrict__ z_tm1,
                                         const float* __restrict__ emb_W,
                                         const float* __restrict__ ctrl_W,
                                         const float* __restrict__ ctrl_b,
                                         float* __restrict__ hW,
                                         float* __restrict__ embed,
                                         unsigned short* __restrict__ Bs,
                                         float* sh) {
    if (blk < 64) {
        int b = blk, h = tid;
        sh[h] = last_hidden[b * HH + h];
        __syncthreads();
        const float4* wrow = (const float4*)(attn_W + (size_t)h * (2 * HH));
        float acc = attn_b[h];
        for (int k4 = 0; k4 < HH / 4; ++k4) {
            float4 w = wrow[k4];
            acc += sh[k4*4+0]*w.x + sh[k4*4+1]*w.y + sh[k4*4+2]*w.z + sh[k4*4+3]*w.w;
        }
        hW[b * HH + h] = acc;
    } else if (blk < 96) {
        int idx = (blk - 64) * 256 + tid;  // 8192 total
        int lane = idx & 63;
        int gt = (idx >> 6) & 15;
        int ks = idx >> 10;
        int col = gt * 16 + (lane & 15);
        int k0 = ks * 32 + (lane >> 4) * 8;
        const float* src = attn_W + (size_t)col * (2 * HH) + HH + k0;
        unsigned int p0 = f2bf(src[0]) | ((unsigned int)f2bf(src[1]) << 16);
        unsigned int p1 = f2bf(src[2]) | ((unsigned int)f2bf(src[3]) << 16);
        unsigned int p2 = f2bf(src[4]) | ((unsigned int)f2bf(src[5]) << 16);
        unsigned int p3 = f2bf(src[6]) | ((unsigned int)f2bf(src[7]) << 16);
        *(uint4*)(Bs + (size_t)idx * 8) = make_uint4(p0, p1, p2, p3);
        __syncthreads();
    } else {
        int b = blk - 96;
        if (tid < EE) sh[tid] = emb_W[(size_t)z_tm1[b] * EE + tid];
        __syncthreads();
        if (tid < EE) {
            const float4* wrow = (const float4*)(ctrl_W + (size_t)tid * EE);
            float acc = ctrl_b[tid] + sh[tid];
            for (int k4 = 0; k4 < EE / 4; ++k4) {
                float4 w = wrow[k4];
                acc += sh[k4*4+0]*w.x + sh[k4*4+1]*w.y + sh[k4*4+2]*w.z + sh[k4*4+3]*w.w;
            }
            embed[b * EE + tid] = acc;
        }
    }
}

__global__ __launch_bounds__(256) void k_pre(const float* __restrict__ last_hidden,
                                             const float* __restrict__ attn_W,
                                             const float* __restrict__ attn_b,
                                             const int* __restrict__ z_tm1,
                                             const float* __restrict__ emb_W,
                                             const float* __restrict__ ctrl_W,
                                             const float* __restrict__ ctrl_b,
                                             float* __restrict__ hW,
                                             float* __restrict__ embed,
                                             unsigned short* __restrict__ Bs) {
    __shared__ float sh[HH];
    pre_body(blockIdx.x, threadIdx.x, last_hidden, attn_W, attn_b, z_tm1, emb_W,
             ctrl_W, ctrl_b, hW, embed, Bs, sh);
}

// INSTRUMENT
__global__ __launch_bounds__(256) void k_pre_x32(const float* __restrict__ last_hidden,
                                                 const float* __restrict__ attn_W,
                                                 const float* __restrict__ attn_b,
                                                 const int* __restrict__ z_tm1,
                                                 const float* __restrict__ emb_W,
                                                 const float* __restrict__ ctrl_W,
                                                 const float* __restrict__ ctrl_b,
                                                 float* __restrict__ hW,
                                                 float* __restrict__ embed,
                                                 unsigned short* __restrict__ Bs) {
    __shared__ float sh[HH];
    for (int rep = 0; rep < 32; ++rep) {
        __syncthreads();
        pre_body(blockIdx.x, threadIdx.x, last_hidden, attn_W, attn_b, z_tm1, emb_W,
                 ctrl_W, ctrl_b, hW, embed, Bs, sh);
    }
}

// ================= K2: scores via bf16 MFMA (unchanged from r4) =================
__global__ __launch_bounds__(256) void k_scores_mfma(const float* __restrict__ enc,
                                                     const unsigned short* __restrict__ Bs,
                                                     const float* __restrict__ attn_v,
                                                     const float* __restrict__ hW,
                                                     float* __restrict__ scores) {
    __shared__ uint4 AbufV[1024];
    __shared__ float scpart[4][32];
    unsigned char* Abuf = (unsigned char*)AbufV;

    int i0 = blockIdx.x * 32;
    int tid = threadIdx.x;

    const float4* src = (const float4*)(enc + (size_t)i0 * HH);
#pragma unroll
    for (int it = 0; it < 4; ++it) {
        int c = tid + it * 256;
        int row = c >> 5;
        int kc = c & 31;
        float4 f0 = src[c * 2];
        float4 f1 = src[c * 2 + 1];
        unsigned int p0 = f2bf(f0.x) | ((unsigned int)f2bf(f0.y) << 16);
        unsigned int p1 = f2bf(f0.z) | ((unsigned int)f2bf(f0.w) << 16);
        unsigned int p2 = f2bf(f1.x) | ((unsigned int)f2bf(f1.y) << 16);
        unsigned int p3 = f2bf(f1.z) | ((unsigned int)f2bf(f1.w) << 16);
        int addr = (row * 512 + kc * 16) ^ ((row & 7) << 4);
        *(uint4*)(Abuf + addr) = make_uint4(p0, p1, p2, p3);
    }
    __syncthreads();

    int wv = tid >> 6, lane = tid & 63;
    int lrow = lane & 15, q = lane >> 4;

    f32x4 acc[2][4];
#pragma unroll
    for (int rt = 0; rt < 2; ++rt)
#pragma unroll
        for (int ct = 0; ct < 4; ++ct) acc[rt][ct] = (f32x4){0.f, 0.f, 0.f, 0.f};

    const bf16x8* BsV = (const bf16x8*)Bs;
    for (int ks = 0; ks < 8; ++ks) {
        bf16x8 bfr[4];
        const bf16x8* bsrc = BsV + ((size_t)(ks * 16 + wv * 4) * 64 + lane);
#pragma unroll
        for (int ct = 0; ct < 4; ++ct) bfr[ct] = bsrc[ct * 64];
        bf16x8 afr[2];
#pragma unroll
        for (int rt = 0; rt < 2; ++rt) {
            int arow = rt * 16 + lrow;
            int abyte = (arow * 512 + ks * 64 + q * 16) ^ ((arow & 7) << 4);
            afr[rt] = *(const bf16x8*)(Abuf + abyte);
        }
#pragma unroll
        for (int rt = 0; rt < 2; ++rt)
#pragma unroll
            for (int ct = 0; ct < 4; ++ct)
                acc[rt][ct] = __builtin_amdgcn_mfma_f32_16x16x32_bf16(afr[rt], bfr[ct], acc[rt][ct], 0, 0, 0);
    }

    float vvv[4];
#pragma unroll
    for (int ct = 0; ct < 4; ++ct) vvv[ct] = attn_v[wv * 64 + ct * 16 + lrow];

#pragma unroll
    for (int rt = 0; rt < 2; ++rt) {
        float ps[4];
#pragma unroll
        for (int r = 0; r < 4; ++r) {
            int i = i0 + rt * 16 + q * 4 + r;
            int b = i & (BB - 1);
            const float* hwb = hW + (size_t)b * HH + wv * 64 + lrow;
            float s = 0.f;
#pragma unroll
            for (int ct = 0; ct < 4; ++ct)
                s += vvv[ct] * ftanh(acc[rt][ct][r] + hwb[ct * 16]);
#pragma unroll
            for (int off = 1; off < 16; off <<= 1) s += __shfl_xor(s, off, 64);
            ps[r] = s;
        }
        if (lrow == 0) {
#pragma unroll
            for (int r = 0; r < 4; ++r) scpart[wv][rt * 16 + q * 4 + r] = ps[r];
        }
    }
    __syncthreads();
    if (tid < 32) {
        float s = scpart[0][tid] + scpart[1][tid] + scpart[2][tid] + scpart[3][tid];
        scores[i0 + tid] = s;
    }
}

// ================= K3 body: softmax+ctx+hidden+gen+probas-stats =================
// smem carve (floats): wbuf[512]@0, part[4096]@512, fin[640]@4608, hid[256]@5248,
// genl[128]@5504, red[128]@5632, slotL[2048 ints]@5760. total 7808.
__device__ __forceinline__ void post_body(int b, int tid,
                                          const float* __restrict__ enc,
                                          const float* __restrict__ scores,
                                          const float* __restrict__ embed,
                                          const float* __restrict__ last_hidden,
                                          const float* __restrict__ Whid,
                                          const float* __restrict__ bhid,
                                          const float* __restrict__ Wout,
                                          const float* __restrict__ bout,
                                          const int* __restrict__ slot,
                                          float* __restrict__ out_hidden,
                                          float* __restrict__ gen,
                                          float* __restrict__ pvals,
                                          float* __restrict__ pbase,
                                          float* smem) {
    float* wbuf = smem;            // 512
    float* part = smem + 512;      // 4096
    float* fin  = smem + 4608;     // 640
    float* hid  = smem + 5248;     // 256
    float* genl = smem + 5504;     // 128
    float* red  = smem + 5632;     // 128
    int*   slotL = (int*)(smem + 5760);  // 2048

    int lane = tid & 63, wv = tid >> 6;

    // ---- phase 0: load slot map (used in phase 5) ----
    slotL[tid] = slot[tid];
    slotL[tid + 1024] = slot[tid + 1024];

    // ---- phase 1: softmax over scores[t*64+b] ----
    float s = (tid < TT) ? scores[tid * BB + b] : -3.0e38f;
    float mx = s;
#pragma unroll
    for (int off = 32; off; off >>= 1) mx = fmaxf(mx, __shfl_xor(mx, off, 64));
    if (lane == 0) red[wv] = mx;
    __syncthreads();
    float m = red[0];
#pragma unroll
    for (int i = 1; i < 16; ++i) m = fmaxf(m, red[i]);
    float e = (tid < TT) ? expf(s - m) : 0.f;
    float sm = e;
#pragma unroll
    for (int off = 32; off; off >>= 1) sm += __shfl_xor(sm, off, 64);
    if (lane == 0) red[16 + wv] = sm;
    __syncthreads();
    float den = 0.f;
#pragma unroll
    for (int i = 0; i < 16; ++i) den += red[16 + i];
    float inv = 1.f / den;
    if (tid < TT) wbuf[tid] = e * inv;
    __syncthreads();

    // ---- phase 2: context, float4, 16-way t-split ----
    {
        int h4 = tid & 63, g = tid >> 6;   // g 0..15 handles t in [g*32, g*32+32)
        f32x4 c4 = {0.f, 0.f, 0.f, 0.f};
        const f32x4* enc4 = (const f32x4*)enc;
        size_t base = ((size_t)(g * 32) * BB + b) * 64 + h4;
#pragma unroll 4
        for (int i = 0; i < 32; ++i) {
            float wt = wbuf[g * 32 + i];
            f32x4 v = enc4[base + (size_t)i * BB * 64];
            c4.x += wt * v.x; c4.y += wt * v.y; c4.z += wt * v.z; c4.w += wt * v.w;
        }
        *(f32x4*)&part[(g * 64 + h4) * 4] = c4;
    }
    __syncthreads();
    // assemble fin = [embed | ctx | last_hidden]
    if (tid < 64) {
        f32x4 t4 = {0.f, 0.f, 0.f, 0.f};
#pragma unroll
        for (int gg = 0; gg < 16; ++gg) {
            f32x4 v = *(const f32x4*)&part[(gg * 64 + tid) * 4];
            t4.x += v.x; t4.y += v.y; t4.z += v.z; t4.w += v.w;
        }
        *(f32x4*)&fin[EE + tid * 4] = t4;
    } else if (tid >= 64 && tid < 96) {
        int j = tid - 64;
        *(f32x4*)&fin[j * 4] = *(const f32x4*)&embed[b * EE + j * 4];
    } else if (tid >= 128 && tid < 192) {
        int j = tid - 128;
        *(f32x4*)&fin[EE + HH + j * 4] = *(const f32x4*)&last_hidden[b * HH + j * 4];
    }
    __syncthreads();

    // ---- phase 3: hidden ----
    {
        int o = tid & 255, kh = tid >> 8;  // kh 0..3, K-chunk 160
        const f32x4* wrow = (const f32x4*)(Whid + (size_t)o * (2 * HH + EE)) + kh * 40;
        const float* fb = fin + kh * 160;
        float a2 = 0.f;
#pragma unroll 8
        for (int k4 = 0; k4 < 40; ++k4) {
            f32x4 ww = wrow[k4];
            a2 += fb[k4*4+0]*ww.x + fb[k4*4+1]*ww.y + fb[k4*4+2]*ww.z + fb[k4*4+3]*ww.w;
        }
        part[kh * 256 + o] = a2;
    }
    __syncthreads();
    if (tid < HH) {
        float hv = fmaxf(part[tid] + part[256 + tid] + part[512 + tid] + part[768 + tid] + bhid[tid], 0.f);
        hid[tid] = hv;
        out_hidden[(size_t)b * HH + tid] = hv;
    }
    __syncthreads();

    // ---- phase 4: gen ----
    {
        int o = tid & 127, q8 = tid >> 7;  // q8 0..7, K-chunk 32
        const f32x4* wrow = (const f32x4*)(Wout + (size_t)o * HH) + q8 * 8;
        const float* hb = hid + q8 * 32;
        float a3 = 0.f;
#pragma unroll
        for (int k4 = 0; k4 < 8; ++k4) {
            f32x4 ww = wrow[k4];
            a3 += hb[k4*4+0]*ww.x + hb[k4*4+1]*ww.y + hb[k4*4+2]*ww.z + hb[k4*4+3]*ww.w;
        }
        part[q8 * 128 + o] = a3;
    }
    __syncthreads();
    if (tid < SS) {
        float gv = bout[tid];
#pragma unroll
        for (int j = 0; j < 8; ++j) gv += part[j * 128 + tid];
        gv = fmaxf(gv, 0.f);
        genl[tid] = gv;
        gen[(size_t)b * SS + tid] = gv;
    }
    __syncthreads();

    // ---- phase 5: probas stats for 16 l's. item A: (lA = tid>>7, sA = tid&127);
    //      item B: (lA+8, sA). threads [l*128, l*128+128) = waves 2l, 2l+1. ----
    {
        int sA = tid & 127, lA = tid >> 7, lB = lA + 8;
        float mgA, mgB;
        bool fA, fB;
        {
            int c = slotL[lA * 128 + sA];
            float sum = 0.f; int fi = SS;
            for (int s2 = 0; s2 < SS; ++s2) {
                if (slotL[lA * 128 + s2] == c) { sum += genl[s2]; if (s2 < fi) fi = s2; }
            }
            mgA = -0.01f + sum; fA = (fi == sA);
        }
        {
            int c = slotL[lB * 128 + sA];
            float sum = 0.f; int fi = SS;
            for (int s2 = 0; s2 < SS; ++s2) {
                if (slotL[lB * 128 + s2] == c) { sum += genl[s2]; if (s2 < fi) fi = s2; }
            }
            mgB = -0.01f + sum; fB = (fi == sA);
        }
        // per-l max over s
        float mA = mgA, mB = mgB;
#pragma unroll
        for (int off = 32; off; off >>= 1) {
            mA = fmaxf(mA, __shfl_xor(mA, off, 64));
            mB = fmaxf(mB, __shfl_xor(mB, off, 64));
        }
        if (lane == 0) { red[wv] = mA; red[16 + wv] = mB; }
        __syncthreads();
        float MA = fmaxf(red[2 * lA], red[2 * lA + 1]);
        float MB = fmaxf(red[16 + 2 * lA], red[16 + 2 * lA + 1]);
        // exp-sum over first-hits + distinct count
        float eA = fA ? expf(mgA - MA) : 0.f;
        float eB = fB ? expf(mgB - MB) : 0.f;
        float cA = fA ? 1.f : 0.f, cB = fB ? 1.f : 0.f;
        float s1 = eA, s2v = cA, s3 = eB, s4 = cB;
#pragma unroll
        for (int off = 32; off; off >>= 1) {
            s1 += __shfl_xor(s1, off, 64);
            s2v += __shfl_xor(s2v, off, 64);
            s3 += __shfl_xor(s3, off, 64);
            s4 += __shfl_xor(s4, off, 64);
        }
        if (lane == 0) { red[32 + wv] = s1; red[48 + wv] = s2v; red[64 + wv] = s3; red[80 + wv] = s4; }
        __syncthreads();
        float sumA = red[32 + 2 * lA] + red[32 + 2 * lA + 1];
        float cntA = red[48 + 2 * lA] + red[48 + 2 * lA + 1];
        float sumB = red[64 + 2 * lA] + red[64 + 2 * lA + 1];
        float cntB = red[80 + 2 * lA] + red[80 + 2 * lA + 1];
        float baseA = expf(-0.01f - MA);
        float invA = 1.f / (((float)VV - cntA) * baseA + sumA);
        float baseB = expf(-0.01f - MB);
        float invB = 1.f / (((float)VV - cntB) * baseB + sumB);
        pvals[((size_t)b * LL + lA) * SS + sA] = fA ? expf(mgA - MA) * invA : -1.f;
        pvals[((size_t)b * LL + lB) * SS + sA] = fB ? expf(mgB - MB) * invB : -1.f;
        if (sA == 0) {
            pbase[b * LL + lA] = baseA * invA;
            pbase[b * LL + lB] = baseB * invB;
        }
    }
    __syncthreads();
}

__global__ __launch_bounds__(1024) void k_post(const float* __restrict__ enc,
                                               const float* __restrict__ scores,
                                               const float* __restrict__ embed,
                                               const float* __restrict__ last_hidden,
                                               const float* __restrict__ Whid,
                                               const float* __restrict__ bhid,
                                               const float* __restrict__ Wout,
                                               const float* __restrict__ bout,
                                               const int* __restrict__ slot,
                                               float* __restrict__ out_hidden,
                                               float* __restrict__ gen,
                                               float* __restrict__ pvals,
                                               float* __restrict__ pbase) {
    __shared__ __align__(16) float smem[7808];
    post_body(blockIdx.x, threadIdx.x, enc, scores, embed, last_hidden, Whid, bhid,
              Wout, bout, slot, out_hidden, gen, pvals, pbase, smem);
}

// INSTRUMENT
__global__ __launch_bounds__(1024) void k_post_x8(const float* __restrict__ enc,
                                                  const float* __restrict__ scores,
                                                  const float* __restrict__ embed,
                                                  const float* __restrict__ last_hidden,
                                                  const float* __restrict__ Whid,
                                                  const float* __restrict__ bhid,
                                                  const float* __restrict__ Wout,
                                                  const float* __restrict__ bout,
                                                  const int* __restrict__ slot,
                                                  float* __restrict__ out_hidden,
                                                  float* __restrict__ gen,
                                                  float* __restrict__ pvals,
                                                  float* __restrict__ pbase) {
    __shared__ __align__(16) float smem[7808];
    for (int rep = 0; rep < 8; ++rep) {
        __syncthreads();
        post_body(blockIdx.x, threadIdx.x, enc, scores, embed, last_hidden, Whid, bhid,
                  Wout, bout, slot, out_hidden, gen, pvals, pbase, smem);
    }
}

// ================= K4: pure streaming fill + scatter =================
__global__ __launch_bounds__(256) void k_fill(const int* __restrict__ slot,
                                              const float* __restrict__ pvals,
                                              const float* __restrict__ pbase,
                                              float* __restrict__ out) {
    int l = blockIdx.x / BB;
    int b = blockIdx.x % BB;
    int tid = threadIdx.x;
    __shared__ float pv[SS];
    __shared__ int cls[SS];
    if (tid < SS) {
        pv[tid] = pvals[((size_t)b * LL + l) * SS + tid];
        cls[tid] = slot[l * SS + tid];
    }
    float pb = pbase[b * LL + l];
    float* row = out + BB * HH + ((size_t)(l * BB + b)) * VV;
    float4 p4 = make_float4(pb, pb, pb, pb);
    float4* row4 = (float4*)row;
    for (int idx = tid; idx < VV / 4; idx += 256) row4[idx] = p4;
    __syncthreads();
    if (tid < SS && pv[tid] >= 0.f) row[cls[tid]] = pv[tid];
}

// INSTRUMENT: per-launch overhead probe
__global__ void k_nop() {}

extern "C" void kernel_launch(void* const* d_in, const int* in_sizes, int n_in,
                              void* d_out, int out_size, void* d_ws, size_t ws_size,
                              hipStream_t stream) {
    const float* u_enc       = (const float*)d_in[0];
    const float* last_hidden = (const float*)d_in[1];
    const int*   z_tm1       = (const int*)d_in[2];
    const int*   slot        = (const int*)d_in[3];
    const float* emb_W       = (const float*)d_in[4];
    const float* ctrl_W      = (const float*)d_in[5];
    const float* ctrl_b      = (const float*)d_in[6];
    const float* attn_W      = (const float*)d_in[7];
    const float* attn_b      = (const float*)d_in[8];
    const float* attn_v      = (const float*)d_in[9];
    const float* Whid        = (const float*)d_in[10];
    const float* bhid        = (const float*)d_in[11];
    const float* Wout        = (const float*)d_in[12];
    const float* bout        = (const float*)d_in[13];
    float* out = (float*)d_out;
    float* ws = (float*)d_ws;

    float* scores = ws;              // 32768
    float* hW     = ws + 32768;      // 16384
    float* embed  = ws + 49152;      // 8192
    float* gen    = ws + 57344;      // 8192
    unsigned short* Bs = (unsigned short*)(ws + 65536);  // 65536 bf16 -> 32768 f
    float* pvals  = ws + 98304;      // 131072
    float* pbase  = ws + 229376;     // 1024

    k_pre<<<160, 256, 0, stream>>>(last_hidden, attn_W, attn_b, z_tm1, emb_W, ctrl_W,
                                   ctrl_b, hW, embed, Bs);
    k_scores_mfma<<<(TT * BB) / 32, 256, 0, stream>>>(u_enc, Bs, attn_v, hW, scores);
    k_post<<<BB, 1024, 0, stream>>>(u_enc, scores, embed, last_hidden, Whid, bhid,
                                    Wout, bout, slot, out, gen, pvals, pbase);
    k_fill<<<LL * BB, 256, 0, stream>>>(slot, pvals, pbase, out);

    // ---- instruments: scratch-only, deterministic ----
    if (ws_size >= ((size_t)8 << 20)) {
        float* hW2    = ws + 262144;
        float* embed2 = ws + 278528;
        unsigned short* Bs2 = (unsigned short*)(ws + 286720);
        float* hid2   = ws + 524288;
        float* gen2   = ws + 540672;
        float* pvals2 = ws + 548864;
        float* pbase2 = ws + 679936;
        k_pre_x32<<<160, 256, 0, stream>>>(last_hidden, attn_W, attn_b, z_tm1, emb_W,
                                           ctrl_W, ctrl_b, hW2, embed2, Bs2);
        k_post_x8<<<BB, 1024, 0, stream>>>(u_enc, scores, embed, last_hidden, Whid, bhid,
                                           Wout, bout, slot, hid2, gen2, pvals2, pbase2);
        for (int i = 0; i < 8; ++i) k_nop<<<1, 64, 0, stream>>>();
    }
}

// Round 7
// 98.775 us; speedup vs baseline: 7.2763x; 7.2763x over previous
//
#include <hip/hip_runtime.h>
#include <hip/hip_bf16.h>

#define BB 64
#define TT 512
#define HH 256
#define EE 128
#define VV 32000
#define SS 128
#define LL 16

typedef __attribute__((ext_vector_type(8))) short bf16x8;
typedef __attribute__((ext_vector_type(4))) float f32x4;

static __device__ __forceinline__ unsigned short f2bf(float x) {
    unsigned int u = __float_as_uint(x);
    unsigned int r = (u + 0x7fffu + ((u >> 16) & 1u)) >> 16;
    return (unsigned short)r;
}

// tanh(x) = 1 - 2/(exp2(x*2*log2e)+1)
static __device__ __forceinline__ float ftanh(float x) {
    float y = __builtin_amdgcn_exp2f(x * 2.885390082f);
    return 1.f - 2.f * __builtin_amdgcn_rcpf(y + 1.f);
}

// ================= K1: {hW, prep_b, embed} by blockIdx =================
__global__ __launch_bounds__(256) void k_pre(const float* __restrict__ last_hidden,
                                             const float* __restrict__ attn_W,
                                             const float* __restrict__ attn_b,
                                             const int* __restrict__ z_tm1,
                                             const float* __restrict__ emb_W,
                                             const float* __restrict__ ctrl_W,
                                             const float* __restrict__ ctrl_b,
                                             float* __restrict__ hW,
                                             float* __restrict__ embed,
                                             unsigned short* __restrict__ Bs) {
    __shared__ float sh[HH];
    int blk = blockIdx.x;
    int tid = threadIdx.x;
    if (blk < 64) {
        int b = blk, h = tid;
        sh[h] = last_hidden[b * HH + h];
        __syncthreads();
        const float4* wrow = (const float4*)(attn_W + (size_t)h * (2 * HH));
        float acc = attn_b[h];
        for (int k4 = 0; k4 < HH / 4; ++k4) {
            float4 w = wrow[k4];
            acc += sh[k4*4+0]*w.x + sh[k4*4+1]*w.y + sh[k4*4+2]*w.z + sh[k4*4+3]*w.w;
        }
        hW[b * HH + h] = acc;
    } else if (blk < 96) {
        // Bs layout: [kstep 0..7][tile 0..15][lane 0..63][8 bf16]
        int idx = (blk - 64) * 256 + tid;  // 8192 total
        int lane = idx & 63;
        int gt = (idx >> 6) & 15;
        int ks = idx >> 10;
        int col = gt * 16 + (lane & 15);
        int k0 = ks * 32 + (lane >> 4) * 8;
        const float* src = attn_W + (size_t)col * (2 * HH) + HH + k0;
        unsigned int p0 = f2bf(src[0]) | ((unsigned int)f2bf(src[1]) << 16);
        unsigned int p1 = f2bf(src[2]) | ((unsigned int)f2bf(src[3]) << 16);
        unsigned int p2 = f2bf(src[4]) | ((unsigned int)f2bf(src[5]) << 16);
        unsigned int p3 = f2bf(src[6]) | ((unsigned int)f2bf(src[7]) << 16);
        *(uint4*)(Bs + (size_t)idx * 8) = make_uint4(p0, p1, p2, p3);
    } else {
        int b = blk - 96;
        if (tid < EE) sh[tid] = emb_W[(size_t)z_tm1[b] * EE + tid];
        __syncthreads();
        if (tid < EE) {
            const float4* wrow = (const float4*)(ctrl_W + (size_t)tid * EE);
            float acc = ctrl_b[tid] + sh[tid];
            for (int k4 = 0; k4 < EE / 4; ++k4) {
                float4 w = wrow[k4];
                acc += sh[k4*4+0]*w.x + sh[k4*4+1]*w.y + sh[k4*4+2]*w.z + sh[k4*4+3]*w.w;
            }
            embed[b * EE + tid] = acc;
        }
    }
}

// ================= K2: scores via bf16 MFMA -> scoresT[b][t] =================
__global__ __launch_bounds__(256) void k_scores_mfma(const float* __restrict__ enc,
                                                     const unsigned short* __restrict__ Bs,
                                                     const float* __restrict__ attn_v,
                                                     const float* __restrict__ hW,
                                                     float* __restrict__ scoresT) {
    __shared__ uint4 AbufV[1024];
    __shared__ float scpart[4][32];
    unsigned char* Abuf = (unsigned char*)AbufV;

    int i0 = blockIdx.x * 32;
    int tid = threadIdx.x;

    const float4* src = (const float4*)(enc + (size_t)i0 * HH);
#pragma unroll
    for (int it = 0; it < 4; ++it) {
        int c = tid + it * 256;
        int row = c >> 5;
        int kc = c & 31;
        float4 f0 = src[c * 2];
        float4 f1 = src[c * 2 + 1];
        unsigned int p0 = f2bf(f0.x) | ((unsigned int)f2bf(f0.y) << 16);
        unsigned int p1 = f2bf(f0.z) | ((unsigned int)f2bf(f0.w) << 16);
        unsigned int p2 = f2bf(f1.x) | ((unsigned int)f2bf(f1.y) << 16);
        unsigned int p3 = f2bf(f1.z) | ((unsigned int)f2bf(f1.w) << 16);
        int addr = (row * 512 + kc * 16) ^ ((row & 7) << 4);
        *(uint4*)(Abuf + addr) = make_uint4(p0, p1, p2, p3);
    }
    __syncthreads();

    int wv = tid >> 6, lane = tid & 63;
    int lrow = lane & 15, q = lane >> 4;

    f32x4 acc[2][4];
#pragma unroll
    for (int rt = 0; rt < 2; ++rt)
#pragma unroll
        for (int ct = 0; ct < 4; ++ct) acc[rt][ct] = (f32x4){0.f, 0.f, 0.f, 0.f};

    const bf16x8* BsV = (const bf16x8*)Bs;
    for (int ks = 0; ks < 8; ++ks) {
        bf16x8 bfr[4];
        const bf16x8* bsrc = BsV + ((size_t)(ks * 16 + wv * 4) * 64 + lane);
#pragma unroll
        for (int ct = 0; ct < 4; ++ct) bfr[ct] = bsrc[ct * 64];
        bf16x8 afr[2];
#pragma unroll
        for (int rt = 0; rt < 2; ++rt) {
            int arow = rt * 16 + lrow;
            int abyte = (arow * 512 + ks * 64 + q * 16) ^ ((arow & 7) << 4);
            afr[rt] = *(const bf16x8*)(Abuf + abyte);
        }
#pragma unroll
        for (int rt = 0; rt < 2; ++rt)
#pragma unroll
            for (int ct = 0; ct < 4; ++ct)
                acc[rt][ct] = __builtin_amdgcn_mfma_f32_16x16x32_bf16(afr[rt], bfr[ct], acc[rt][ct], 0, 0, 0);
    }

    float vvv[4];
#pragma unroll
    for (int ct = 0; ct < 4; ++ct) vvv[ct] = attn_v[wv * 64 + ct * 16 + lrow];

#pragma unroll
    for (int rt = 0; rt < 2; ++rt) {
        float ps[4];
#pragma unroll
        for (int r = 0; r < 4; ++r) {
            int i = i0 + rt * 16 + q * 4 + r;
            int b = i & (BB - 1);
            const float* hwb = hW + (size_t)b * HH + wv * 64 + lrow;
            float s = 0.f;
#pragma unroll
            for (int ct = 0; ct < 4; ++ct)
                s += vvv[ct] * ftanh(acc[rt][ct][r] + hwb[ct * 16]);
#pragma unroll
            for (int off = 1; off < 16; off <<= 1) s += __shfl_xor(s, off, 64);
            ps[r] = s;
        }
        if (lrow == 0) {
#pragma unroll
            for (int r = 0; r < 4; ++r) scpart[wv][rt * 16 + q * 4 + r] = ps[r];
        }
    }
    __syncthreads();
    if (tid < 32) {
        float s = scpart[0][tid] + scpart[1][tid] + scpart[2][tid] + scpart[3][tid];
        int i = i0 + tid;                       // i = t*B + b
        scoresT[(i & 63) * TT + (i >> 6)] = s;  // [b][t]
    }
}

// ================= K3a: context partials, 1024 blocks =================
// block bx: c = bx>>6 (t-chunk of 32), b = bx&63. Recomputes softmax stats
// from scoresT[b][:] (2KB), accumulates 32 enc rows into partial[c][b][:].
__global__ __launch_bounds__(256) void k_ctx(const float* __restrict__ enc,
                                             const float* __restrict__ scoresT,
                                             float* __restrict__ partial) {
    __shared__ float red[8];
    __shared__ float wloc[32];
    __shared__ float part[4][256];
    int bx = blockIdx.x;
    int c = bx >> 6, b = bx & 63;
    int tid = threadIdx.x;
    int lane = tid & 63, wv = tid >> 6;

    float s0 = scoresT[b * TT + 2 * tid];
    float s1 = scoresT[b * TT + 2 * tid + 1];
    float mx = fmaxf(s0, s1);
#pragma unroll
    for (int off = 32; off; off >>= 1) mx = fmaxf(mx, __shfl_xor(mx, off, 64));
    if (lane == 0) red[wv] = mx;
    __syncthreads();
    float m = fmaxf(fmaxf(red[0], red[1]), fmaxf(red[2], red[3]));
    float e0 = expf(s0 - m), e1 = expf(s1 - m);
    float sm = e0 + e1;
#pragma unroll
    for (int off = 32; off; off >>= 1) sm += __shfl_xor(sm, off, 64);
    if (lane == 0) red[4 + wv] = sm;
    __syncthreads();
    float inv = 1.f / (red[4] + red[5] + red[6] + red[7]);
    if (tid < 32) wloc[tid] = expf(scoresT[b * TT + c * 32 + tid] - m) * inv;
    __syncthreads();

    int h4 = tid & 63, g = tid >> 6;  // g handles t = c*32 + g*8 + i
    f32x4 c4 = {0.f, 0.f, 0.f, 0.f};
    const f32x4* enc4 = (const f32x4*)enc;
    size_t base = ((size_t)(c * 32 + g * 8) * BB + b) * 64 + h4;
#pragma unroll
    for (int i = 0; i < 8; ++i) {
        float wt = wloc[g * 8 + i];
        f32x4 v = enc4[base + (size_t)i * BB * 64];
        c4.x += wt * v.x; c4.y += wt * v.y; c4.z += wt * v.z; c4.w += wt * v.w;
    }
    *(f32x4*)&part[g][h4 * 4] = c4;
    __syncthreads();
    if (tid < 64) {
        f32x4 a0 = *(const f32x4*)&part[0][tid * 4];
        f32x4 a1 = *(const f32x4*)&part[1][tid * 4];
        f32x4 a2 = *(const f32x4*)&part[2][tid * 4];
        f32x4 a3 = *(const f32x4*)&part[3][tid * 4];
        f32x4 t4;
        t4.x = a0.x + a1.x + a2.x + a3.x;
        t4.y = a0.y + a1.y + a2.y + a3.y;
        t4.z = a0.z + a1.z + a2.z + a3.z;
        t4.w = a0.w + a1.w + a2.w + a3.w;
        *(f32x4*)&partial[((size_t)c * BB + b) * HH + tid * 4] = t4;
    }
}

// ================= K3b: partial-sum + hidden + gen + probas-stats =================
__global__ __launch_bounds__(1024) void k_ffnn(const float* __restrict__ partial,
                                               const float* __restrict__ embed,
                                               const float* __restrict__ last_hidden,
                                               const float* __restrict__ Whid,
                                               const float* __restrict__ bhid,
                                               const float* __restrict__ Wout,
                                               const float* __restrict__ bout,
                                               const int* __restrict__ slot,
                                               float* __restrict__ out_hidden,
                                               float* __restrict__ gen,
                                               float* __restrict__ pvals,
                                               float* __restrict__ pbase) {
    __shared__ __align__(16) float part[1024];
    __shared__ __align__(16) float fin[2 * HH + EE];
    __shared__ float hid[HH];
    __shared__ float genl[SS];
    __shared__ float red[128];
    __shared__ int slotL[LL * SS];
    int b = blockIdx.x;
    int tid = threadIdx.x;
    int lane = tid & 63, wv = tid >> 6;

    slotL[tid] = slot[tid];
    slotL[tid + 1024] = slot[tid + 1024];

    // phase A: sum 16 partials (4 per thread-group)
    {
        int h = tid & 255, pc = tid >> 8;
        float a = 0.f;
#pragma unroll
        for (int j = 0; j < 4; ++j)
            a += partial[((size_t)(pc * 4 + j) * BB + b) * HH + h];
        part[pc * 256 + h] = a;
    }
    __syncthreads();
    if (tid < 256) fin[EE + tid] = part[tid] + part[256 + tid] + part[512 + tid] + part[768 + tid];
    else if (tid < 384) fin[tid - 256] = embed[b * EE + (tid - 256)];
    else if (tid < 640) fin[EE + HH + (tid - 384)] = last_hidden[b * HH + (tid - 384)];
    __syncthreads();

    // phase B: hidden
    {
        int o = tid & 255, kh = tid >> 8;
        const f32x4* wrow = (const f32x4*)(Whid + (size_t)o * (2 * HH + EE)) + kh * 40;
        const float* fb = fin + kh * 160;
        float a2 = 0.f;
#pragma unroll 8
        for (int k4 = 0; k4 < 40; ++k4) {
            f32x4 ww = wrow[k4];
            a2 += fb[k4*4+0]*ww.x + fb[k4*4+1]*ww.y + fb[k4*4+2]*ww.z + fb[k4*4+3]*ww.w;
        }
        part[kh * 256 + o] = a2;
    }
    __syncthreads();
    if (tid < HH) {
        float hv = fmaxf(part[tid] + part[256 + tid] + part[512 + tid] + part[768 + tid] + bhid[tid], 0.f);
        hid[tid] = hv;
        out_hidden[(size_t)b * HH + tid] = hv;
    }
    __syncthreads();

    // phase C: gen
    {
        int o = tid & 127, q8 = tid >> 7;
        const f32x4* wrow = (const f32x4*)(Wout + (size_t)o * HH) + q8 * 8;
        const float* hb = hid + q8 * 32;
        float a3 = 0.f;
#pragma unroll
        for (int k4 = 0; k4 < 8; ++k4) {
            f32x4 ww = wrow[k4];
            a3 += hb[k4*4+0]*ww.x + hb[k4*4+1]*ww.y + hb[k4*4+2]*ww.z + hb[k4*4+3]*ww.w;
        }
        part[q8 * 128 + o] = a3;
    }
    __syncthreads();
    if (tid < SS) {
        float gv = bout[tid];
#pragma unroll
        for (int j = 0; j < 8; ++j) gv += part[j * 128 + tid];
        gv = fmaxf(gv, 0.f);
        genl[tid] = gv;
        gen[(size_t)b * SS + tid] = gv;
    }
    __syncthreads();

    // phase D: probas stats, 16 l's (item A: l=tid>>7, item B: l+8)
    {
        int sA = tid & 127, lA = tid >> 7, lB = lA + 8;
        float mgA, mgB;
        bool fA, fB;
        {
            int c = slotL[lA * 128 + sA];
            float sum = 0.f; int fi = SS;
            for (int s2 = 0; s2 < SS; ++s2) {
                if (slotL[lA * 128 + s2] == c) { sum += genl[s2]; if (s2 < fi) fi = s2; }
            }
            mgA = -0.01f + sum; fA = (fi == sA);
        }
        {
            int c = slotL[lB * 128 + sA];
            float sum = 0.f; int fi = SS;
            for (int s2 = 0; s2 < SS; ++s2) {
                if (slotL[lB * 128 + s2] == c) { sum += genl[s2]; if (s2 < fi) fi = s2; }
            }
            mgB = -0.01f + sum; fB = (fi == sA);
        }
        float mA = mgA, mB = mgB;
#pragma unroll
        for (int off = 32; off; off >>= 1) {
            mA = fmaxf(mA, __shfl_xor(mA, off, 64));
            mB = fmaxf(mB, __shfl_xor(mB, off, 64));
        }
        if (lane == 0) { red[wv] = mA; red[16 + wv] = mB; }
        __syncthreads();
        float MA = fmaxf(red[2 * lA], red[2 * lA + 1]);
        float MB = fmaxf(red[16 + 2 * lA], red[16 + 2 * lA + 1]);
        float eA = fA ? expf(mgA - MA) : 0.f;
        float eB = fB ? expf(mgB - MB) : 0.f;
        float cA = fA ? 1.f : 0.f, cB = fB ? 1.f : 0.f;
        float s1 = eA, s2v = cA, s3 = eB, s4 = cB;
#pragma unroll
        for (int off = 32; off; off >>= 1) {
            s1 += __shfl_xor(s1, off, 64);
            s2v += __shfl_xor(s2v, off, 64);
            s3 += __shfl_xor(s3, off, 64);
            s4 += __shfl_xor(s4, off, 64);
        }
        if (lane == 0) { red[32 + wv] = s1; red[48 + wv] = s2v; red[64 + wv] = s3; red[80 + wv] = s4; }
        __syncthreads();
        float sumA = red[32 + 2 * lA] + red[32 + 2 * lA + 1];
        float cntA = red[48 + 2 * lA] + red[48 + 2 * lA + 1];
        float sumB = red[64 + 2 * lA] + red[64 + 2 * lA + 1];
        float cntB = red[80 + 2 * lA] + red[80 + 2 * lA + 1];
        float baseA = expf(-0.01f - MA);
        float invA = 1.f / (((float)VV - cntA) * baseA + sumA);
        float baseB = expf(-0.01f - MB);
        float invB = 1.f / (((float)VV - cntB) * baseB + sumB);
        pvals[((size_t)b * LL + lA) * SS + sA] = fA ? expf(mgA - MA) * invA : -1.f;
        pvals[((size_t)b * LL + lB) * SS + sA] = fB ? expf(mgB - MB) * invB : -1.f;
        if (sA == 0) {
            pbase[b * LL + lA] = baseA * invA;
            pbase[b * LL + lB] = baseB * invB;
        }
    }
}

// ================= K4: streaming fill + scatter, half-rows =================
__global__ __launch_bounds__(256) void k_fill(const int* __restrict__ slot,
                                              const float* __restrict__ pvals,
                                              const float* __restrict__ pbase,
                                              float* __restrict__ out) {
    int bx = blockIdx.x;
    int row = bx >> 1, half = bx & 1;
    int l = row >> 6, b = row & 63;
    int tid = threadIdx.x;
    __shared__ float pv[SS];
    __shared__ int cls[SS];
    if (tid < SS) {
        pv[tid] = pvals[((size_t)b * LL + l) * SS + tid];
        cls[tid] = slot[l * SS + tid];
    }
    float pb = pbase[b * LL + l];
    float* rowp = out + BB * HH + ((size_t)(l * BB + b)) * VV;
    float4 p4 = make_float4(pb, pb, pb, pb);
    float4* row4 = (float4*)rowp + half * (VV / 8);
#pragma unroll 4
    for (int idx = tid; idx < VV / 8; idx += 256) row4[idx] = p4;
    __syncthreads();
    if (tid < SS && pv[tid] >= 0.f) {
        int c = cls[tid];
        int lo = half * (VV / 2);
        if (c >= lo && c < lo + VV / 2) rowp[c] = pv[tid];
    }
}

extern "C" void kernel_launch(void* const* d_in, const int* in_sizes, int n_in,
                              void* d_out, int out_size, void* d_ws, size_t ws_size,
                              hipStream_t stream) {
    const float* u_enc       = (const float*)d_in[0];
    const float* last_hidden = (const float*)d_in[1];
    const int*   z_tm1       = (const int*)d_in[2];
    const int*   slot        = (const int*)d_in[3];
    const float* emb_W       = (const float*)d_in[4];
    const float* ctrl_W      = (const float*)d_in[5];
    const float* ctrl_b      = (const float*)d_in[6];
    const float* attn_W      = (const float*)d_in[7];
    const float* attn_b      = (const float*)d_in[8];
    const float* attn_v      = (const float*)d_in[9];
    const float* Whid        = (const float*)d_in[10];
    const float* bhid        = (const float*)d_in[11];
    const float* Wout        = (const float*)d_in[12];
    const float* bout        = (const float*)d_in[13];
    float* out = (float*)d_out;
    float* ws = (float*)d_ws;

    float* scoresT = ws;             // 32768 ([b][t])
    float* hW      = ws + 32768;     // 16384
    float* embed   = ws + 49152;     // 8192
    float* gen     = ws + 57344;     // 8192
    unsigned short* Bs = (unsigned short*)(ws + 65536);  // 65536 bf16
    float* pvals   = ws + 98304;     // 131072
    float* pbase   = ws + 229376;    // 1024
    float* partial = ws + 230400;    // 16*64*256 = 262144

    k_pre<<<160, 256, 0, stream>>>(last_hidden, attn_W, attn_b, z_tm1, emb_W, ctrl_W,
                                   ctrl_b, hW, embed, Bs);
    k_scores_mfma<<<(TT * BB) / 32, 256, 0, stream>>>(u_enc, Bs, attn_v, hW, scoresT);
    k_ctx<<<16 * BB, 256, 0, stream>>>(u_enc, scoresT, partial);
    k_ffnn<<<BB, 1024, 0, stream>>>(partial, embed, last_hidden, Whid, bhid,
                                    Wout, bout, slot, out, gen, pvals, pbase);
    k_fill<<<LL * BB * 2, 256, 0, stream>>>(slot, pvals, pbase, out);
}